// Round 12
// baseline (2276.640 us; speedup 1.0000x reference)
//
#include <hip/hip_runtime.h>
#include <math.h>
#include <stdint.h>

#define B_ 4
#define S_ 1024
#define E_ 768
#define H_ 3072
#define V_ 16384
#define L_ 5
#define T_TOK 4096   // B_*S_

typedef unsigned short u16;
typedef short bf16x8 __attribute__((ext_vector_type(8)));
typedef float floatx4 __attribute__((ext_vector_type(4)));
typedef u16 u16x4 __attribute__((ext_vector_type(4)));
typedef u16 u16x8 __attribute__((ext_vector_type(8)));

__device__ __forceinline__ u16 f2bf(float f) {
    union { float f; unsigned u; } x; x.f = f;
    unsigned r = (x.u + 0x7FFFu + ((x.u >> 16) & 1u)) >> 16;
    return (u16)r;
}
__device__ __forceinline__ float bf2f(u16 v) {
    union { unsigned u; float f; } x; x.u = ((unsigned)v) << 16;
    return x.f;
}

__device__ __forceinline__ void gload16(const void* g, void* l) {
    __builtin_amdgcn_global_load_lds(
        (const __attribute__((address_space(1))) unsigned int*)(uintptr_t)g,
        (__attribute__((address_space(3))) unsigned int*)(uintptr_t)l,
        16, 0, 0);
}

__device__ __forceinline__ void bar_sync() {
    asm volatile("s_waitcnt vmcnt(0)" ::: "memory");
    __builtin_amdgcn_s_barrier();
    asm volatile("" ::: "memory");
}

// rope rotate helper: v at column col (pair = lane^1), i = (col>>1)%384
__device__ __forceinline__ float rope_rot(float v, long row, long col, int lane,
                                          const float2* __restrict__ tab) {
    float vp = __shfl_xor(v, 1, 64);
    int s = (int)(row & (S_ - 1));
    int ii = ((int)col >> 1) % 384;
    float2 f = tab[(long)s * 384 + ii];
    return (lane & 1) ? (vp * f.y + v * f.x) : (v * f.x - vp * f.y);
}

#define BK 32

// ---------------------------------------------------------------------------
// 128x128 2-phase kernel. BIAS: 0 none, 1 per-col, 2 per-row.
template<int OBF, int RELU, int BIAS, int ROPE>
__global__ __launch_bounds__(256) void mgemm(
    const u16* __restrict__ A, const u16* __restrict__ B, void* __restrict__ Cv,
    const float* __restrict__ bias, const float2* __restrict__ tab,
    float alpha, int M, int N, int K,
    int lda, int ldb, int ldc,
    long sA, long sB, long sC, long sBias)
{
    __shared__ u16 As[2][128 * BK];
    __shared__ u16 Bs[2][128 * BK];

    const int tid  = threadIdx.x;
    const int lane = tid & 63;
    const int wid  = tid >> 6;
    const int wr   = (wid >> 1) * 64;
    const int wc   = (wid & 1) * 64;
    const int lr   = lane & 15;
    const int kg   = lane >> 4;

    const long rowBase = (long)blockIdx.y * 128;
    const long colBase = (long)blockIdx.x * 128;

    const u16* Ab = A + (long)blockIdx.z * sA;
    const u16* Bb = B + (long)blockIdx.z * sB;
    const float* biasz = bias ? bias + (long)blockIdx.z * sBias : bias;

    const int c0 = tid, c1 = tid + 256;
    const int ar0 = c0 >> 2, ac0 = (c0 & 3) ^ ((ar0 >> 1) & 3);
    const int ar1 = c1 >> 2, ac1 = (c1 & 3) ^ ((ar1 >> 1) & 3);

    const u16* pa0 = Ab + (rowBase + ar0) * (long)lda + ac0 * 8;
    const u16* pa1 = Ab + (rowBase + ar1) * (long)lda + ac1 * 8;
    const u16* pb0 = Bb + (colBase + ar0) * (long)ldb + ac0 * 8;
    const u16* pb1 = Bb + (colBase + ar1) * (long)ldb + ac1 * 8;

    int aoff[4], boff[4];
    #pragma unroll
    for (int m = 0; m < 4; ++m) {
        int r = wr + m * 16 + lr;
        aoff[m] = r * 32 + ((kg ^ ((r >> 1) & 3)) << 3);
        int c = wc + m * 16 + lr;
        boff[m] = c * 32 + ((kg ^ ((c >> 1) & 3)) << 3);
    }

    floatx4 acc[4][4];
    #pragma unroll
    for (int m = 0; m < 4; ++m)
        #pragma unroll
        for (int n = 0; n < 4; ++n)
            acc[m][n] = (floatx4)0.f;

    auto stage = [&](int buf, int k0) {
        gload16(pa0 + k0, &As[buf][c0 * 8]);
        gload16(pa1 + k0, &As[buf][c1 * 8]);
        gload16(pb0 + k0, &Bs[buf][c0 * 8]);
        gload16(pb1 + k0, &Bs[buf][c1 * 8]);
    };

    const int NT = K / BK;
    stage(0, 0);
    bar_sync();

    for (int t = 0; t < NT; ++t) {
        const int cur = t & 1;
        if (t + 1 < NT) stage(cur ^ 1, (t + 1) * BK);

        bf16x8 af[4], bfr[4];
        #pragma unroll
        for (int m = 0; m < 4; ++m) af[m]  = *(const bf16x8*)(&As[cur][aoff[m]]);
        #pragma unroll
        for (int n = 0; n < 4; ++n) bfr[n] = *(const bf16x8*)(&Bs[cur][boff[n]]);
        #pragma unroll
        for (int m = 0; m < 4; ++m)
            #pragma unroll
            for (int n = 0; n < 4; ++n)
                acc[m][n] = __builtin_amdgcn_mfma_f32_16x16x32_bf16(
                                af[m], bfr[n], acc[m][n], 0, 0, 0);

        if (t + 1 < NT) bar_sync();
    }

    const long col0 = colBase + wc + lr;
    const long row0 = rowBase + wr + kg * 4;
    #pragma unroll
    for (int n = 0; n < 4; ++n) {
        long col = col0 + n * 16;
        float bvc = (BIAS == 1) ? biasz[col] : 0.f;
        #pragma unroll
        for (int m = 0; m < 4; ++m)
            #pragma unroll
            for (int j = 0; j < 4; ++j) {
                long row = row0 + m * 16 + j;
                float v = acc[m][n][j] * alpha + bvc;
                if (BIAS == 2) v += biasz[row];
                if (ROPE) v = rope_rot(v, row, col, lane, tab);
                if (RELU) v = fmaxf(v, 0.f);
                if (OBF) ((u16*)Cv + (long)blockIdx.z * sC)[row * (long)ldc + col] = f2bf(v);
                else     ((float*)Cv + (long)blockIdx.z * sC)[row * (long)ldc + col] = v;
            }
    }
}

// ---------------------------------------------------------------------------
// 64x128 2-phase kernel (N=768-class / attention GEMMs).
// cmode: 0 none; 1 causal qkt block-skip (cols>rows fully masked -> return);
//        2 causal pv K-trim (P cols beyond rowBase+63 are exact zeros).
template<int OBF, int RELU, int BIAS, int ROPE>
__global__ __launch_bounds__(256) void mgemm64(
    const u16* __restrict__ A, const u16* __restrict__ B, void* __restrict__ Cv,
    const float* __restrict__ bias, const float2* __restrict__ tab,
    float alpha, int M, int N, int K,
    int lda, int ldb, int ldc,
    long sA, long sB, long sC, long sBias, int cmode)
{
    __shared__ u16 As[2][64 * BK];
    __shared__ u16 Bs[2][128 * BK];

    const int tid  = threadIdx.x;
    const int lane = tid & 63;
    const int wid  = tid >> 6;
    const int lr   = lane & 15;
    const int kg   = lane >> 4;

    const long rowBase = (long)blockIdx.y * 64;
    const long colBase = (long)blockIdx.x * 128;

    if (cmode == 1 && colBase > rowBase + 63) return;   // fully-masked qkt tile

    const u16* Ab = A + (long)blockIdx.z * sA;
    const u16* Bb = B + (long)blockIdx.z * sB;
    const float* biasz = bias ? bias + (long)blockIdx.z * sBias : bias;

    const int ra = tid >> 2, cha = (tid & 3) ^ ((ra >> 1) & 3);
    const int c0 = tid, c1 = tid + 256;
    const int rb0 = c0 >> 2, chb0 = (c0 & 3) ^ ((rb0 >> 1) & 3);
    const int rb1 = c1 >> 2, chb1 = (c1 & 3) ^ ((rb1 >> 1) & 3);

    const u16* pa  = Ab + (rowBase + ra)  * (long)lda + cha  * 8;
    const u16* pb0 = Bb + (colBase + rb0) * (long)ldb + chb0 * 8;
    const u16* pb1 = Bb + (colBase + rb1) * (long)ldb + chb1 * 8;

    int aoff[4], boff[2];
    #pragma unroll
    for (int m = 0; m < 4; ++m) {
        int r = m * 16 + lr;
        aoff[m] = r * 32 + ((kg ^ ((r >> 1) & 3)) << 3);
    }
    #pragma unroll
    for (int n = 0; n < 2; ++n) {
        int c = wid * 32 + n * 16 + lr;
        boff[n] = c * 32 + ((kg ^ ((c >> 1) & 3)) << 3);
    }

    floatx4 acc[4][2];
    #pragma unroll
    for (int m = 0; m < 4; ++m)
        #pragma unroll
        for (int n = 0; n < 2; ++n)
            acc[m][n] = (floatx4)0.f;

    auto stage = [&](int buf, int k0) {
        gload16(pa  + k0, &As[buf][tid * 8]);
        gload16(pb0 + k0, &Bs[buf][c0 * 8]);
        gload16(pb1 + k0, &Bs[buf][c1 * 8]);
    };

    int NT = K / BK;
    if (cmode == 2) {                     // pv: keys beyond rowBase+63 give 0
        int lim = (int)(rowBase >> 5) + 2;
        if (lim < NT) NT = lim;
    }
    stage(0, 0);
    bar_sync();

    for (int t = 0; t < NT; ++t) {
        const int cur = t & 1;
        if (t + 1 < NT) stage(cur ^ 1, (t + 1) * BK);

        bf16x8 af[4], bfr[2];
        #pragma unroll
        for (int m = 0; m < 4; ++m) af[m]  = *(const bf16x8*)(&As[cur][aoff[m]]);
        #pragma unroll
        for (int n = 0; n < 2; ++n) bfr[n] = *(const bf16x8*)(&Bs[cur][boff[n]]);
        #pragma unroll
        for (int m = 0; m < 4; ++m)
            #pragma unroll
            for (int n = 0; n < 2; ++n)
                acc[m][n] = __builtin_amdgcn_mfma_f32_16x16x32_bf16(
                                af[m], bfr[n], acc[m][n], 0, 0, 0);

        if (t + 1 < NT) bar_sync();
    }

    const long col0 = colBase + wid * 32 + lr;
    const long row0 = rowBase + kg * 4;
    #pragma unroll
    for (int n = 0; n < 2; ++n) {
        long col = col0 + n * 16;
        float bvc = (BIAS == 1) ? biasz[col] : 0.f;
        #pragma unroll
        for (int m = 0; m < 4; ++m)
            #pragma unroll
            for (int j = 0; j < 4; ++j) {
                long row = row0 + m * 16 + j;
                float v = acc[m][n][j] * alpha + bvc;
                if (BIAS == 2) v += biasz[row];
                if (ROPE) v = rope_rot(v, row, col, lane, tab);
                if (RELU) v = fmaxf(v, 0.f);
                if (OBF) ((u16*)Cv + (long)blockIdx.z * sC)[row * (long)ldc + col] = f2bf(v);
                else     ((float*)Cv + (long)blockIdx.z * sC)[row * (long)ldc + col] = v;
            }
    }
}

// ---------------------------------------------------------------------------
// 256x256 8-wave phase-split pipelined GEMM — unembed only (1024 blocks).
// XCD-aware block swizzle (T1): grid must satisfy nwg % 8 == 0.
template<int OBF, int RELU, int BIAS>
__global__ __launch_bounds__(512, 2) void mgemm8(
    const u16* __restrict__ A, const u16* __restrict__ B, void* __restrict__ Cv,
    const float* __restrict__ bias, float alpha, int M, int N, int K,
    int lda, int ldb, int ldc)
{
    __shared__ u16 As[3][256 * 32];
    __shared__ u16 Bs[3][256 * 32];

    const int tid  = threadIdx.x;
    const int lane = tid & 63;
    const int wid  = tid >> 6;
    const int wm   = wid >> 2;
    const int wn   = wid & 3;
    const int lr   = lane & 15;
    const int kg   = lane >> 4;

    const int wgid = blockIdx.y * gridDim.x + blockIdx.x;
    const int cpx  = (gridDim.x * gridDim.y) >> 3;
    const int swz  = (wgid & 7) * cpx + (wgid >> 3);
    const int bx   = swz % gridDim.x;
    const int by   = swz / gridDim.x;

    const long rowBase = (long)by * 256;
    const long colBase = (long)bx * 256;

    const int c0 = tid, c1 = tid + 512;
    const int r0 = c0 >> 2, ch0 = (c0 & 3) ^ ((r0 >> 1) & 3);
    const int r1 = c1 >> 2, ch1 = (c1 & 3) ^ ((r1 >> 1) & 3);

    const u16* pa0 = A + (rowBase + r0) * (long)lda + ch0 * 8;
    const u16* pa1 = A + (rowBase + r1) * (long)lda + ch1 * 8;
    const u16* pb0 = B + (colBase + r0) * (long)ldb + ch0 * 8;
    const u16* pb1 = B + (colBase + r1) * (long)ldb + ch1 * 8;

    int aoff[8], boff[4];
    #pragma unroll
    for (int mi = 0; mi < 8; ++mi) {
        int r = wm * 128 + mi * 16 + lr;
        aoff[mi] = r * 32 + ((kg ^ ((r >> 1) & 3)) << 3);
    }
    #pragma unroll
    for (int ni = 0; ni < 4; ++ni) {
        int c = wn * 64 + ni * 16 + lr;
        boff[ni] = c * 32 + ((kg ^ ((c >> 1) & 3)) << 3);
    }

    floatx4 acc[8][4];
    #pragma unroll
    for (int mi = 0; mi < 8; ++mi)
        #pragma unroll
        for (int ni = 0; ni < 4; ++ni)
            acc[mi][ni] = (floatx4)0.f;

    auto stageA = [&](int buf, int kt) {
        gload16(pa0 + (long)kt * 32, &As[buf][c0 * 8]);
        gload16(pa1 + (long)kt * 32, &As[buf][c1 * 8]);
    };
    auto stageB = [&](int buf, int kt) {
        gload16(pb0 + (long)kt * 32, &Bs[buf][c0 * 8]);
        gload16(pb1 + (long)kt * 32, &Bs[buf][c1 * 8]);
    };

    const int NT = K / 32;
    stageA(0, 0); stageB(0, 0);
    stageA(1, 1); stageB(1, 1);
    asm volatile("s_waitcnt vmcnt(4)" ::: "memory");
    __builtin_amdgcn_sched_barrier(0);
    __builtin_amdgcn_s_barrier();

    int b0 = 0, b1 = 1, b2 = 2;
    for (int t = 0; t < NT; ++t) {
        bf16x8 afr[4], bfr[4];
        if (t + 2 < NT) stageA(b2, t + 2);
        #pragma unroll
        for (int mi = 0; mi < 4; ++mi) afr[mi] = *(const bf16x8*)(&As[b0][aoff[mi]]);
        #pragma unroll
        for (int ni = 0; ni < 4; ++ni) bfr[ni] = *(const bf16x8*)(&Bs[b0][boff[ni]]);
        __builtin_amdgcn_s_barrier();
        asm volatile("s_waitcnt lgkmcnt(0)" ::: "memory");
        __builtin_amdgcn_sched_barrier(0);
        __builtin_amdgcn_s_setprio(1);
        #pragma unroll
        for (int mi = 0; mi < 4; ++mi)
            #pragma unroll
            for (int ni = 0; ni < 4; ++ni)
                acc[mi][ni] = __builtin_amdgcn_mfma_f32_16x16x32_bf16(
                                  afr[mi], bfr[ni], acc[mi][ni], 0, 0, 0);
        __builtin_amdgcn_s_setprio(0);
        __builtin_amdgcn_sched_barrier(0);
        __builtin_amdgcn_s_barrier();
        if (t + 2 < NT) stageB(b2, t + 2);
        #pragma unroll
        for (int mi = 0; mi < 4; ++mi) afr[mi] = *(const bf16x8*)(&As[b0][aoff[4 + mi]]);
        __builtin_amdgcn_s_barrier();
        asm volatile("s_waitcnt lgkmcnt(0)" ::: "memory");
        __builtin_amdgcn_sched_barrier(0);
        __builtin_amdgcn_s_setprio(1);
        #pragma unroll
        for (int mi = 0; mi < 4; ++mi)
            #pragma unroll
            for (int ni = 0; ni < 4; ++ni)
                acc[4 + mi][ni] = __builtin_amdgcn_mfma_f32_16x16x32_bf16(
                                      afr[mi], bfr[ni], acc[4 + mi][ni], 0, 0, 0);
        __builtin_amdgcn_s_setprio(0);
        __builtin_amdgcn_sched_barrier(0);
        if (t + 2 < NT) { asm volatile("s_waitcnt vmcnt(4)" ::: "memory"); }
        else            { asm volatile("s_waitcnt vmcnt(0)" ::: "memory"); }
        __builtin_amdgcn_sched_barrier(0);
        __builtin_amdgcn_s_barrier();
        int tb = b0; b0 = b1; b1 = b2; b2 = tb;
    }

    const long col0 = colBase + wn * 64 + lr;
    const long row0 = rowBase + wm * 128 + kg * 4;
    #pragma unroll
    for (int ni = 0; ni < 4; ++ni) {
        long col = col0 + ni * 16;
        float bv = BIAS ? bias[col] : 0.f;
        #pragma unroll
        for (int mi = 0; mi < 8; ++mi)
            #pragma unroll
            for (int j = 0; j < 4; ++j) {
                float v = acc[mi][ni][j] * alpha + bv;
                if (RELU) v = fmaxf(v, 0.f);
                if (OBF) ((u16*)Cv)[(row0 + mi * 16 + j) * (long)ldc + col] = f2bf(v);
                else     ((float*)Cv)[(row0 + mi * 16 + j) * (long)ldc + col] = v;
            }
    }
}

// ---------------------------------------------------------------------------
// fp32 [R][C] -> bf16 [C][R] weight transpose-convert. 64x64 tiles.
__global__ __launch_bounds__(256) void tcvt(
    const float* __restrict__ in, u16* __restrict__ out,
    int ldIn, int ldOut, long sIn, long sOut)
{
    __shared__ u16 t[64][68];
    const int tx = threadIdx.x & 15;
    const int ty = threadIdx.x >> 4;
    const long r0 = (long)blockIdx.y * 64, c0 = (long)blockIdx.x * 64;
    const float* ib = in + (long)blockIdx.z * sIn;
    u16* ob = out + (long)blockIdx.z * sOut;
    #pragma unroll
    for (int j = 0; j < 4; ++j) {
        int r = ty + j * 16;
        float4 v = *(const float4*)&ib[(r0 + r) * (long)ldIn + c0 + tx * 4];
        u16x4 q = { f2bf(v.x), f2bf(v.y), f2bf(v.z), f2bf(v.w) };
        *(u16x4*)&t[r][tx * 4] = q;
    }
    __syncthreads();
    #pragma unroll
    for (int j = 0; j < 4; ++j) {
        int c = ty + j * 16;
        u16x4 q = { t[tx*4+0][c], t[tx*4+1][c], t[tx*4+2][c], t[tx*4+3][c] };
        *(u16x4*)&ob[(c0 + c) * (long)ldOut + r0 + tx * 4] = q;
    }
}

// ---------------------------------------------------------------------------
__global__ __launch_bounds__(256) void gather_kernel(
    const int* __restrict__ seq, const float* __restrict__ embed,
    u16* __restrict__ xb)
{
    int t = blockIdx.x;
    int tok = seq[t];
    const float* src = embed + (long)tok * E_;
    long base = (long)t * E_;
    #pragma unroll
    for (int j = 0; j < 3; ++j) {
        int i = threadIdx.x + j * 256;
        xb[base + i] = f2bf(src[i]);
    }
}

// ---------------------------------------------------------------------------
__global__ __launch_bounds__(384) void rope_tab_kernel(float2* __restrict__ tab)
{
    int s = blockIdx.x;
    int i = threadIdx.x;
    float inv = expf(-(float)(2 * i) * (9.210340371976184f / (float)E_));
    float ang = (float)s * inv;
    float sn, cs;
    sincosf(ang, &sn, &cs);
    tab[(long)s * 384 + i] = make_float2(cs, sn);
}

// ---------------------------------------------------------------------------
// In-place softmax on bf16 scores (scale pre-applied). One WAVE per row,
// 4 rows per block; 16 elems/lane via 16B loads; pure shuffle reduce.
__global__ __launch_bounds__(256) void softmax_kernel(
    u16* __restrict__ P, int causal)
{
    const int w = threadIdx.x >> 6;
    const int lane = threadIdx.x & 63;
    const long row = (long)blockIdx.x * 4 + w;
    const int s = (int)(row & (S_ - 1));
    u16* p = P + row * S_;
    const int c0 = lane * 16;

    u16x8 a = *(const u16x8*)(p + c0);
    u16x8 b = *(const u16x8*)(p + c0 + 8);
    float v[16];
    float mx = -INFINITY;
    #pragma unroll
    for (int j = 0; j < 8; ++j) {
        float x = bf2f((u16)a[j]);
        if (causal && c0 + j > s) x = -INFINITY;
        v[j] = x; mx = fmaxf(mx, x);
    }
    #pragma unroll
    for (int j = 0; j < 8; ++j) {
        float x = bf2f((u16)b[j]);
        if (causal && c0 + 8 + j > s) x = -INFINITY;
        v[8 + j] = x; mx = fmaxf(mx, x);
    }
    #pragma unroll
    for (int off = 1; off < 64; off <<= 1)
        mx = fmaxf(mx, __shfl_xor(mx, off, 64));

    float sum = 0.f;
    #pragma unroll
    for (int j = 0; j < 16; ++j) {
        v[j] = __expf(v[j] - mx);
        sum += v[j];
    }
    #pragma unroll
    for (int off = 1; off < 64; off <<= 1)
        sum += __shfl_xor(sum, off, 64);

    float invs = 1.f / sum;
    u16x8 oa, ob;
    #pragma unroll
    for (int j = 0; j < 8; ++j) oa[j] = f2bf(v[j] * invs);
    #pragma unroll
    for (int j = 0; j < 8; ++j) ob[j] = f2bf(v[8 + j] * invs);
    *(u16x8*)(p + c0) = oa;
    *(u16x8*)(p + c0 + 8) = ob;
}

// ---------------------------------------------------------------------------
// xout = LN(xin + hin)*g + b, all bf16 (fp32 stats). One WAVE per row.
__global__ __launch_bounds__(256) void add_ln_kernel(
    const u16* __restrict__ xin, const u16* __restrict__ hin,
    const float* __restrict__ gb, u16* __restrict__ xout)
{
    int row = blockIdx.x * 4 + (threadIdx.x >> 6);
    int lane = threadIdx.x & 63;
    const u16x4* xr = (const u16x4*)(xin + (long)row * E_);
    const u16x4* hr = (const u16x4*)(hin + (long)row * E_);

    float4 v[3];
    float sum = 0.f, sq = 0.f;
    #pragma unroll
    for (int l = 0; l < 3; ++l) {
        int idx = l * 64 + lane;
        u16x4 a = xr[idx];
        u16x4 b = hr[idx];
        v[l].x = bf2f(a[0]) + bf2f(b[0]);
        v[l].y = bf2f(a[1]) + bf2f(b[1]);
        v[l].z = bf2f(a[2]) + bf2f(b[2]);
        v[l].w = bf2f(a[3]) + bf2f(b[3]);
        sum += v[l].x + v[l].y + v[l].z + v[l].w;
        sq  += v[l].x*v[l].x + v[l].y*v[l].y + v[l].z*v[l].z + v[l].w*v[l].w;
    }
    #pragma unroll
    for (int off = 1; off < 64; off <<= 1) {
        sum += __shfl_xor(sum, off, 64);
        sq  += __shfl_xor(sq,  off, 64);
    }

    float mu  = sum * (1.f / E_);
    float var = sq * (1.f / E_) - mu * mu;
    float inv = rsqrtf(var + 1e-5f);

    const float4* g4 = (const float4*)gb;
    const float4* b4 = (const float4*)(gb + E_);
    u16x4* xo = (u16x4*)(xout + (long)row * E_);
    #pragma unroll
    for (int l = 0; l < 3; ++l) {
        int idx = l * 64 + lane;
        float4 g = g4[idx], bb = b4[idx];
        u16x4 ob;
        ob[0] = f2bf((v[l].x - mu) * inv * g.x + bb.x);
        ob[1] = f2bf((v[l].y - mu) * inv * g.y + bb.y);
        ob[2] = f2bf((v[l].z - mu) * inv * g.z + bb.z);
        ob[3] = f2bf((v[l].w - mu) * inv * g.w + bb.w);
        xo[idx] = ob;
    }
}

// ---------------------------------------------------------------------------
// MLP tail: h = relu(p0 + p1 + b2); xout = LN(xin + h)*g + b. One WAVE per row.
__global__ __launch_bounds__(256) void add_ln_mlp_kernel(
    const u16* __restrict__ xin, const u16* __restrict__ part,
    const float* __restrict__ b2, const float* __restrict__ gb,
    u16* __restrict__ xout)
{
    const long TE = (long)T_TOK * E_;
    int row = blockIdx.x * 4 + (threadIdx.x >> 6);
    int lane = threadIdx.x & 63;
    const u16x4* xr = (const u16x4*)(xin + (long)row * E_);
    const u16x4* p0 = (const u16x4*)(part + (long)row * E_);
    const u16x4* p1 = (const u16x4*)(part + TE + (long)row * E_);
    const float4* b24 = (const float4*)b2;

    float4 v[3];
    float sum = 0.f, sq = 0.f;
    #pragma unroll
    for (int l = 0; l < 3; ++l) {
        int idx = l * 64 + lane;
        u16x4 a = xr[idx];
        u16x4 h0 = p0[idx];
        u16x4 h1 = p1[idx];
        float4 bv = b24[idx];
        float h;
        h = fmaxf(bf2f(h0[0]) + bf2f(h1[0]) + bv.x, 0.f); v[l].x = bf2f(a[0]) + h;
        h = fmaxf(bf2f(h0[1]) + bf2f(h1[1]) + bv.y, 0.f); v[l].y = bf2f(a[1]) + h;
        h = fmaxf(bf2f(h0[2]) + bf2f(h1[2]) + bv.z, 0.f); v[l].z = bf2f(a[2]) + h;
        h = fmaxf(bf2f(h0[3]) + bf2f(h1[3]) + bv.w, 0.f); v[l].w = bf2f(a[3]) + h;
        sum += v[l].x + v[l].y + v[l].z + v[l].w;
        sq  += v[l].x*v[l].x + v[l].y*v[l].y + v[l].z*v[l].z + v[l].w*v[l].w;
    }
    #pragma unroll
    for (int off = 1; off < 64; off <<= 1) {
        sum += __shfl_xor(sum, off, 64);
        sq  += __shfl_xor(sq,  off, 64);
    }

    float mu  = sum * (1.f / E_);
    float var = sq * (1.f / E_) - mu * mu;
    float inv = rsqrtf(var + 1e-5f);

    const float4* g4 = (const float4*)gb;
    const float4* b4 = (const float4*)(gb + E_);
    u16x4* xo = (u16x4*)(xout + (long)row * E_);
    #pragma unroll
    for (int l = 0; l < 3; ++l) {
        int idx = l * 64 + lane;
        float4 g = g4[idx], bb = b4[idx];
        u16x4 ob;
        ob[0] = f2bf((v[l].x - mu) * inv * g.x + bb.x);
        ob[1] = f2bf((v[l].y - mu) * inv * g.y + bb.y);
        ob[2] = f2bf((v[l].z - mu) * inv * g.z + bb.z);
        ob[3] = f2bf((v[l].w - mu) * inv * g.w + bb.w);
        xo[idx] = ob;
    }
}

// ---------------------------------------------------------------------------
extern "C" void kernel_launch(void* const* d_in, const int* in_sizes, int n_in,
                              void* d_out, int out_size, void* d_ws, size_t ws_size,
                              hipStream_t stream) {
    const int*   seq       = (const int*)d_in[0];
    const float* embed     = (const float*)d_in[2];
    const float* enc_qkv_w = (const float*)d_in[3];
    const float* enc_qkv_b = (const float*)d_in[4];
    const float* enc_ln    = (const float*)d_in[5];
    const float* enc_w1    = (const float*)d_in[6];
    const float* enc_b1    = (const float*)d_in[7];
    const float* enc_w2    = (const float*)d_in[8];
    const float* enc_b2    = (const float*)d_in[9];
    const float* dec_qkv_w = (const float*)d_in[10];
    const float* dec_qkv_b = (const float*)d_in[11];
    const float* dec_ln    = (const float*)d_in[12];
    const float* dec_w1    = (const float*)d_in[13];
    const float* dec_b1    = (const float*)d_in[14];
    const float* dec_w2    = (const float*)d_in[15];
    const float* dec_b2    = (const float*)d_in[16];
    const float* unembed   = (const float*)d_in[17];

    const long TE  = (long)T_TOK * E_;
    const long SE  = (long)S_ * E_;
    const long SS  = (long)S_ * S_;
    const long EE  = (long)E_ * E_;
    const long EH  = (long)E_ * H_;
    const long VE  = (long)V_ * E_;
    const long SQK = (long)S_ * 1536;
    const long TABF = (long)S_ * 384 * 2;   // floats

    float*  ws    = (float*)d_ws;
    float2* f_tab = (float2*)ws;

    u16* u_emb = (u16*)(ws + TABF);     // TE
    u16* u_x   = u_emb + TE;            // TE  (bf16 residual state)
    u16* u_h   = u_x + TE;              // TE  (attn output)
    u16* u_enc = u_h + TE;              // 5*TE
    u16* u_R   = u_enc + 5 * TE;        // 4*TE: qk(2TE)+vT(TE) | hid(4TE)
    u16* u_s2  = u_R + 4 * TE;          // 2*TE: P | mlp partials
    u16* u_ck  = u_s2 + 2 * TE;         // 5*TE  cross-K [T][768] per layer
    u16* u_cv  = u_ck + 5 * TE;         // 5*TE  cross-V^T [768][T] per layer
    u16* u_w   = u_cv + 5 * TE;         // weights

    u16* u_qk  = u_R;
    u16* u_vT  = u_R + 2 * TE;
    u16* u_hid = u_R;
    u16* u_P   = u_s2;

    // weight region: MLP+unembed first (tier 1), QKV after (tier 2)
    u16* pw_ew1  = u_w;
    u16* pw_ew2  = pw_ew1 + 5 * EH;
    u16* pw_dw1  = pw_ew2 + 5 * EH;
    u16* pw_dw2  = pw_dw1 + 5 * EH;
    u16* pw_un   = pw_dw2 + 5 * EH;
    u16* pw_eqkv = pw_un + VE;
    u16* pw_dqkv = pw_eqkv + 15 * EE;

    size_t need_full = (size_t)((char*)(pw_dqkv + 30 * EE) - (char*)d_ws);
    size_t need_mid  = (size_t)((char*)(pw_eqkv + 2 * EE) - (char*)d_ws);
    bool pQKV = ws_size >= need_full;
    bool pMLP = ws_size >= need_mid;

    auto T = [&](const float* in, u16* out, int R, int C, int z) {
        dim3 g(C / 64, R / 64, z);
        tcvt<<<g, 256, 0, stream>>>(in, out, C, R, (long)R * C, (long)R * C);
    };
    auto WTq = [&](const float* w, int z, u16* pp) -> const u16* {
        if (pQKV) return pp;
        u16* dst = pMLP ? pw_eqkv : u_w;
        T(w, dst, E_, E_, z);
        return dst;
    };
    auto WTm = [&](const float* w, int R, int C, u16* pp) -> const u16* {
        if (pMLP) return pp;
        T(w, u_w, R, C, 1);
        return u_w;
    };

    if (pQKV) {
        T(enc_qkv_w, pw_eqkv, E_, E_, 15);
        T(dec_qkv_w, pw_dqkv, E_, E_, 30);
    }
    if (pMLP) {
        T(enc_w1, pw_ew1, E_, H_, L_);
        T(enc_w2, pw_ew2, H_, E_, L_);
        T(dec_w1, pw_dw1, E_, H_, L_);
        T(dec_w2, pw_dw2, H_, E_, L_);
        T(unembed, pw_un, E_, V_, 1);
    }

    rope_tab_kernel<<<S_, 384, 0, stream>>>(f_tab);
    gather_kernel<<<T_TOK, 256, 0, stream>>>(seq, embed, u_emb);

    const float SCALE = 0.03608439182435161f; // 1/sqrt(768)

    // --- per-op launchers -------------------------------------------------
    auto qk_rope = [&](const u16* X, const u16* W, const float* bias) {
        dim3 g(1536 / 128, T_TOK / 64, 1);   // 64x128 tile: 768 blocks (3/CU)
        mgemm64<1,0,1,1><<<g,256,0,stream>>>(X, W, u_qk, bias, f_tab, 1.f,
            T_TOK, 1536, E_, E_, E_, 1536, 0, 0, 0, 0, 0);
    };
    auto proj_rope64 = [&](const u16* X, const u16* W, u16* dst, const float* bias,
                           int ldc) {
        dim3 g(768 / 128, T_TOK / 64, 1);
        mgemm64<1,0,1,1><<<g,256,0,stream>>>(X, W, dst, bias, f_tab, 1.f,
            T_TOK, 768, E_, E_, E_, ldc, 0, 0, 0, 0, 0);
    };
    auto vT_gemm = [&](const u16* Wv, const u16* X, u16* dst, const float* biasrow) {
        dim3 g(T_TOK / 128, 768 / 64, 1);
        mgemm64<1,0,2,0><<<g,256,0,stream>>>(Wv, X, dst, biasrow, nullptr, 1.f,
            768, T_TOK, E_, E_, E_, T_TOK, 0, 0, 0, 0, 0);
    };
    auto qkt = [&](const u16* Kp, int ldbK, long sB, int causal) {
        dim3 g(S_ / 128, S_ / 64, B_);
        mgemm64<1,0,0,0><<<g,256,0,stream>>>(u_qk, Kp, u_P, nullptr, nullptr,
            SCALE, S_, S_, E_, 1536, ldbK, S_, SQK, sB, SS, 0, causal ? 1 : 0);
    };
    auto pv = [&](const u16* Vp, int causal) {
        dim3 g(E_ / 128, S_ / 64, B_);
        mgemm64<1,0,0,0><<<g,256,0,stream>>>(u_P, Vp, u_h, nullptr, nullptr, 1.f,
            S_, E_, S_, S_, T_TOK, E_, SS, 1024, SE, 0, causal ? 2 : 0);
    };
    auto mlp1 = [&](const u16* X, const u16* W, const float* b1) {
        dim3 g(H_ / 128, T_TOK / 128, 1);
        mgemm<1,1,1,0><<<g,256,0,stream>>>(X, W, u_hid, b1, nullptr, 1.f,
            T_TOK, H_, E_, E_, E_, H_, 0, 0, 0, 0);
    };
    auto mlp2 = [&](const u16* W) {
        dim3 g(E_ / 128, T_TOK / 128, 2);
        mgemm<1,0,0,0><<<g,256,0,stream>>>(u_hid, W, u_s2 + 0, nullptr, nullptr, 1.f,
            T_TOK, E_, 1536, H_, H_, E_, 1536, 1536, TE, 0);
    };
    auto lnz = [&](const u16* xin, const float* gb, u16* xbdst) {
        add_ln_kernel<<<T_TOK / 4, 256, 0, stream>>>(xin, u_h, gb, xbdst);
    };
    auto lnmlp = [&](const u16* xin, const float* b2, const float* gb, u16* xbdst) {
        add_ln_mlp_kernel<<<T_TOK / 4, 256, 0, stream>>>(xin, u_s2, b2, gb, xbdst);
    };
    auto sm = [&](int causal) {
        softmax_kernel<<<T_TOK / 4, 256, 0, stream>>>(u_P, causal);
    };

    // ------------------------ encoder ------------------------
    for (int i = 0; i < L_; ++i) {
        const u16* xsrc = (i == 0) ? u_emb : u_enc + (long)(i - 1) * TE;
        const float* bb = enc_qkv_b + (long)i * 3 * E_;
        qk_rope(xsrc, WTq(enc_qkv_w + (long)i * 3 * EE, 2,
                          pw_eqkv + (long)i * 3 * EE), bb);
        vT_gemm(WTq(enc_qkv_w + ((long)i * 3 + 2) * EE, 1,
                    pw_eqkv + ((long)i * 3 + 2) * EE), xsrc, u_vT, bb + 2 * E_);
        qkt(u_qk + 768, 1536, SQK, 0);
        sm(0);
        pv(u_vT, 0);
        lnz(xsrc, enc_ln + (2L * i + 0) * 2 * E_, u_x);
        mlp1(u_x, WTm(enc_w1 + (long)i * EH, E_, H_, pw_ew1 + (long)i * EH),
             enc_b1 + (long)i * H_);
        mlp2(WTm(enc_w2 + (long)i * EH, H_, E_, pw_ew2 + (long)i * EH));
        lnmlp(u_x, enc_b2 + (long)i * E_, enc_ln + (2L * i + 1) * 2 * E_,
              u_enc + (long)i * TE);
    }

    // ---- batched cross-attention K/V precompute (z = 5 layers) ----
    if (pQKV) {
        {   // cross K: [T][768] per layer, roped, per-col bias (stride 6E)
            dim3 g(768 / 128, T_TOK / 64, L_);
            mgemm64<1,0,1,1><<<g,256,0,stream>>>(
                u_enc, pw_dqkv + 4 * EE, u_ck, dec_qkv_b + 4 * E_, f_tab, 1.f,
                T_TOK, 768, E_, E_, E_, 768, TE, 6 * EE, TE, 6 * E_, 0);
        }
        {   // cross V^T: [768][T] per layer, per-row bias (stride 6E)
            dim3 g(T_TOK / 128, 768 / 64, L_);
            mgemm64<1,0,2,0><<<g,256,0,stream>>>(
                pw_dqkv + 5 * EE, u_enc, u_cv, dec_qkv_b + 5 * E_, nullptr, 1.f,
                768, T_TOK, E_, E_, E_, T_TOK, 6 * EE, TE, TE, 6 * E_, 0);
        }
    }

    // ------------------------ decoder ------------------------
    for (int i = 0; i < L_; ++i) {
        const u16* xs = (i == 0) ? u_emb : u_x;   // no seed copy
        const u16* kv_bf = u_enc + (long)i * TE;
        const float* bb = dec_qkv_b + (long)i * 6 * E_;

        // self-attention (causal)
        qk_rope(xs, WTq(dec_qkv_w + (long)i * 6 * EE, 2,
                        pw_dqkv + (long)i * 6 * EE), bb);
        vT_gemm(WTq(dec_qkv_w + ((long)i * 6 + 2) * EE, 1,
                    pw_dqkv + ((long)i * 6 + 2) * EE), xs, u_vT, bb + 2 * E_);
        qkt(u_qk + 768, 1536, SQK, 1);
        sm(1);
        pv(u_vT, 1);
        lnz(xs, dec_ln + (3L * i + 0) * 2 * E_, u_x);

        // cross-attention: Q per layer; K/V precomputed (batched) if pQKV
        proj_rope64(u_x, WTq(dec_qkv_w + ((long)i * 6 + 3) * EE, 1,
                             pw_dqkv + ((long)i * 6 + 3) * EE), u_qk, bb + 3 * E_, 1536);
        const u16* Vc;
        if (pQKV) {
            qkt(u_ck + (long)i * TE, 768, SE, 0);
            Vc = u_cv + (long)i * TE;
        } else {
            proj_rope64(kv_bf, WTq(dec_qkv_w + ((long)i * 6 + 4) * EE, 1, nullptr),
                        u_qk + 768, bb + 4 * E_, 1536);
            vT_gemm(WTq(dec_qkv_w + ((long)i * 6 + 5) * EE, 1, nullptr),
                    kv_bf, u_vT, bb + 5 * E_);
            qkt(u_qk + 768, 1536, SQK, 0);
            Vc = u_vT;
        }
        sm(0);
        pv(Vc, 0);
        lnz(u_x, dec_ln + (3L * i + 1) * 2 * E_, u_x);

        // MLP
        mlp1(u_x, WTm(dec_w1 + (long)i * EH, E_, H_, pw_dw1 + (long)i * EH),
             dec_b1 + (long)i * H_);
        mlp2(WTm(dec_w2 + (long)i * EH, H_, E_, pw_dw2 + (long)i * EH));
        lnmlp(u_x, dec_b2 + (long)i * E_, dec_ln + (3L * i + 2) * 2 * E_, u_x);
    }

    // ------------------------ unembed ------------------------
    {
        dim3 g(V_ / 256, T_TOK / 256, 1);
        mgemm8<0,0,0><<<g,512,0,stream>>>(u_x, WTm(unembed, E_, V_, pw_un),
            d_out, nullptr, 1.f, T_TOK, V_, E_, E_, E_, V_);
    }
}

// Round 13
// 2257.503 us; speedup vs baseline: 1.0085x; 1.0085x over previous
//
#include <hip/hip_runtime.h>
#include <math.h>
#include <stdint.h>

#define B_ 4
#define S_ 1024
#define E_ 768
#define H_ 3072
#define V_ 16384
#define L_ 5
#define T_TOK 4096   // B_*S_

typedef unsigned short u16;
typedef short bf16x8 __attribute__((ext_vector_type(8)));
typedef float floatx4 __attribute__((ext_vector_type(4)));
typedef u16 u16x4 __attribute__((ext_vector_type(4)));
typedef u16 u16x8 __attribute__((ext_vector_type(8)));

__device__ __forceinline__ u16 f2bf(float f) {
    union { float f; unsigned u; } x; x.f = f;
    unsigned r = (x.u + 0x7FFFu + ((x.u >> 16) & 1u)) >> 16;
    return (u16)r;
}
__device__ __forceinline__ float bf2f(u16 v) {
    union { unsigned u; float f; } x; x.u = ((unsigned)v) << 16;
    return x.f;
}

__device__ __forceinline__ void gload16(const void* g, void* l) {
    __builtin_amdgcn_global_load_lds(
        (const __attribute__((address_space(1))) unsigned int*)(uintptr_t)g,
        (__attribute__((address_space(3))) unsigned int*)(uintptr_t)l,
        16, 0, 0);
}

__device__ __forceinline__ void bar_sync() {
    asm volatile("s_waitcnt vmcnt(0)" ::: "memory");
    __builtin_amdgcn_s_barrier();
    asm volatile("" ::: "memory");
}

// rope rotate helper: v at column col (pair = lane^1), i = (col>>1)%384
__device__ __forceinline__ float rope_rot(float v, long row, long col, int lane,
                                          const float2* __restrict__ tab) {
    float vp = __shfl_xor(v, 1, 64);
    int s = (int)(row & (S_ - 1));
    int ii = ((int)col >> 1) % 384;
    float2 f = tab[(long)s * 384 + ii];
    return (lane & 1) ? (vp * f.y + v * f.x) : (v * f.x - vp * f.y);
}

#define BK 32

// ---------------------------------------------------------------------------
// 128x128 2-phase kernel. BIAS: 0 none, 1 per-col, 2 per-row.
template<int OBF, int RELU, int BIAS, int ROPE>
__global__ __launch_bounds__(256) void mgemm(
    const u16* __restrict__ A, const u16* __restrict__ B, void* __restrict__ Cv,
    const float* __restrict__ bias, const float2* __restrict__ tab,
    float alpha, int M, int N, int K,
    int lda, int ldb, int ldc,
    long sA, long sB, long sC, long sBias)
{
    __shared__ u16 As[2][128 * BK];
    __shared__ u16 Bs[2][128 * BK];

    const int tid  = threadIdx.x;
    const int lane = tid & 63;
    const int wid  = tid >> 6;
    const int wr   = (wid >> 1) * 64;
    const int wc   = (wid & 1) * 64;
    const int lr   = lane & 15;
    const int kg   = lane >> 4;

    const long rowBase = (long)blockIdx.y * 128;
    const long colBase = (long)blockIdx.x * 128;

    const u16* Ab = A + (long)blockIdx.z * sA;
    const u16* Bb = B + (long)blockIdx.z * sB;
    const float* biasz = bias ? bias + (long)blockIdx.z * sBias : bias;

    const int c0 = tid, c1 = tid + 256;
    const int ar0 = c0 >> 2, ac0 = (c0 & 3) ^ ((ar0 >> 1) & 3);
    const int ar1 = c1 >> 2, ac1 = (c1 & 3) ^ ((ar1 >> 1) & 3);

    const u16* pa0 = Ab + (rowBase + ar0) * (long)lda + ac0 * 8;
    const u16* pa1 = Ab + (rowBase + ar1) * (long)lda + ac1 * 8;
    const u16* pb0 = Bb + (colBase + ar0) * (long)ldb + ac0 * 8;
    const u16* pb1 = Bb + (colBase + ar1) * (long)ldb + ac1 * 8;

    int aoff[4], boff[4];
    #pragma unroll
    for (int m = 0; m < 4; ++m) {
        int r = wr + m * 16 + lr;
        aoff[m] = r * 32 + ((kg ^ ((r >> 1) & 3)) << 3);
        int c = wc + m * 16 + lr;
        boff[m] = c * 32 + ((kg ^ ((c >> 1) & 3)) << 3);
    }

    floatx4 acc[4][4];
    #pragma unroll
    for (int m = 0; m < 4; ++m)
        #pragma unroll
        for (int n = 0; n < 4; ++n)
            acc[m][n] = (floatx4)0.f;

    auto stage = [&](int buf, int k0) {
        gload16(pa0 + k0, &As[buf][c0 * 8]);
        gload16(pa1 + k0, &As[buf][c1 * 8]);
        gload16(pb0 + k0, &Bs[buf][c0 * 8]);
        gload16(pb1 + k0, &Bs[buf][c1 * 8]);
    };

    const int NT = K / BK;
    stage(0, 0);
    bar_sync();

    for (int t = 0; t < NT; ++t) {
        const int cur = t & 1;
        if (t + 1 < NT) stage(cur ^ 1, (t + 1) * BK);

        bf16x8 af[4], bfr[4];
        #pragma unroll
        for (int m = 0; m < 4; ++m) af[m]  = *(const bf16x8*)(&As[cur][aoff[m]]);
        #pragma unroll
        for (int n = 0; n < 4; ++n) bfr[n] = *(const bf16x8*)(&Bs[cur][boff[n]]);
        #pragma unroll
        for (int m = 0; m < 4; ++m)
            #pragma unroll
            for (int n = 0; n < 4; ++n)
                acc[m][n] = __builtin_amdgcn_mfma_f32_16x16x32_bf16(
                                af[m], bfr[n], acc[m][n], 0, 0, 0);

        if (t + 1 < NT) bar_sync();
    }

    const long col0 = colBase + wc + lr;
    const long row0 = rowBase + wr + kg * 4;
    #pragma unroll
    for (int n = 0; n < 4; ++n) {
        long col = col0 + n * 16;
        float bvc = (BIAS == 1) ? biasz[col] : 0.f;
        #pragma unroll
        for (int m = 0; m < 4; ++m)
            #pragma unroll
            for (int j = 0; j < 4; ++j) {
                long row = row0 + m * 16 + j;
                float v = acc[m][n][j] * alpha + bvc;
                if (BIAS == 2) v += biasz[row];
                if (ROPE) v = rope_rot(v, row, col, lane, tab);
                if (RELU) v = fmaxf(v, 0.f);
                if (OBF) ((u16*)Cv + (long)blockIdx.z * sC)[row * (long)ldc + col] = f2bf(v);
                else     ((float*)Cv + (long)blockIdx.z * sC)[row * (long)ldc + col] = v;
            }
    }
}

// ---------------------------------------------------------------------------
// 64x128 2-phase kernel (N=768-class / attention GEMMs).
// cmode: 0 none; 1 causal qkt block-skip (cols>rows fully masked -> return);
//        2 causal pv K-trim (P cols beyond rowBase+63 are exact zeros).
template<int OBF, int RELU, int BIAS, int ROPE>
__global__ __launch_bounds__(256) void mgemm64(
    const u16* __restrict__ A, const u16* __restrict__ B, void* __restrict__ Cv,
    const float* __restrict__ bias, const float2* __restrict__ tab,
    float alpha, int M, int N, int K,
    int lda, int ldb, int ldc,
    long sA, long sB, long sC, long sBias, int cmode)
{
    __shared__ u16 As[2][64 * BK];
    __shared__ u16 Bs[2][128 * BK];

    const int tid  = threadIdx.x;
    const int lane = tid & 63;
    const int wid  = tid >> 6;
    const int lr   = lane & 15;
    const int kg   = lane >> 4;

    const long rowBase = (long)blockIdx.y * 64;
    const long colBase = (long)blockIdx.x * 128;

    if (cmode == 1 && colBase > rowBase + 63) return;   // fully-masked qkt tile

    const u16* Ab = A + (long)blockIdx.z * sA;
    const u16* Bb = B + (long)blockIdx.z * sB;
    const float* biasz = bias ? bias + (long)blockIdx.z * sBias : bias;

    const int ra = tid >> 2, cha = (tid & 3) ^ ((ra >> 1) & 3);
    const int c0 = tid, c1 = tid + 256;
    const int rb0 = c0 >> 2, chb0 = (c0 & 3) ^ ((rb0 >> 1) & 3);
    const int rb1 = c1 >> 2, chb1 = (c1 & 3) ^ ((rb1 >> 1) & 3);

    const u16* pa  = Ab + (rowBase + ra)  * (long)lda + cha  * 8;
    const u16* pb0 = Bb + (colBase + rb0) * (long)ldb + chb0 * 8;
    const u16* pb1 = Bb + (colBase + rb1) * (long)ldb + chb1 * 8;

    int aoff[4], boff[2];
    #pragma unroll
    for (int m = 0; m < 4; ++m) {
        int r = m * 16 + lr;
        aoff[m] = r * 32 + ((kg ^ ((r >> 1) & 3)) << 3);
    }
    #pragma unroll
    for (int n = 0; n < 2; ++n) {
        int c = wid * 32 + n * 16 + lr;
        boff[n] = c * 32 + ((kg ^ ((c >> 1) & 3)) << 3);
    }

    floatx4 acc[4][2];
    #pragma unroll
    for (int m = 0; m < 4; ++m)
        #pragma unroll
        for (int n = 0; n < 2; ++n)
            acc[m][n] = (floatx4)0.f;

    auto stage = [&](int buf, int k0) {
        gload16(pa  + k0, &As[buf][tid * 8]);
        gload16(pb0 + k0, &Bs[buf][c0 * 8]);
        gload16(pb1 + k0, &Bs[buf][c1 * 8]);
    };

    int NT = K / BK;
    if (cmode == 2) {                     // pv: keys beyond rowBase+63 give 0
        int lim = (int)(rowBase >> 5) + 2;
        if (lim < NT) NT = lim;
    }
    stage(0, 0);
    bar_sync();

    for (int t = 0; t < NT; ++t) {
        const int cur = t & 1;
        if (t + 1 < NT) stage(cur ^ 1, (t + 1) * BK);

        bf16x8 af[4], bfr[2];
        #pragma unroll
        for (int m = 0; m < 4; ++m) af[m]  = *(const bf16x8*)(&As[cur][aoff[m]]);
        #pragma unroll
        for (int n = 0; n < 2; ++n) bfr[n] = *(const bf16x8*)(&Bs[cur][boff[n]]);
        #pragma unroll
        for (int m = 0; m < 4; ++m)
            #pragma unroll
            for (int n = 0; n < 2; ++n)
                acc[m][n] = __builtin_amdgcn_mfma_f32_16x16x32_bf16(
                                af[m], bfr[n], acc[m][n], 0, 0, 0);

        if (t + 1 < NT) bar_sync();
    }

    const long col0 = colBase + wid * 32 + lr;
    const long row0 = rowBase + kg * 4;
    #pragma unroll
    for (int n = 0; n < 2; ++n) {
        long col = col0 + n * 16;
        float bvc = (BIAS == 1) ? biasz[col] : 0.f;
        #pragma unroll
        for (int m = 0; m < 4; ++m)
            #pragma unroll
            for (int j = 0; j < 4; ++j) {
                long row = row0 + m * 16 + j;
                float v = acc[m][n][j] * alpha + bvc;
                if (BIAS == 2) v += biasz[row];
                if (ROPE) v = rope_rot(v, row, col, lane, tab);
                if (RELU) v = fmaxf(v, 0.f);
                if (OBF) ((u16*)Cv + (long)blockIdx.z * sC)[row * (long)ldc + col] = f2bf(v);
                else     ((float*)Cv + (long)blockIdx.z * sC)[row * (long)ldc + col] = v;
            }
    }
}

// ---------------------------------------------------------------------------
// 256x256 8-wave phase-split pipelined GEMM — unembed only (1024 blocks).
// XCD-aware block swizzle (T1): grid must satisfy nwg % 8 == 0.
template<int OBF, int RELU, int BIAS>
__global__ __launch_bounds__(512, 2) void mgemm8(
    const u16* __restrict__ A, const u16* __restrict__ B, void* __restrict__ Cv,
    const float* __restrict__ bias, float alpha, int M, int N, int K,
    int lda, int ldb, int ldc)
{
    __shared__ u16 As[3][256 * 32];
    __shared__ u16 Bs[3][256 * 32];

    const int tid  = threadIdx.x;
    const int lane = tid & 63;
    const int wid  = tid >> 6;
    const int wm   = wid >> 2;
    const int wn   = wid & 3;
    const int lr   = lane & 15;
    const int kg   = lane >> 4;

    const int wgid = blockIdx.y * gridDim.x + blockIdx.x;
    const int cpx  = (gridDim.x * gridDim.y) >> 3;
    const int swz  = (wgid & 7) * cpx + (wgid >> 3);
    const int bx   = swz % gridDim.x;
    const int by   = swz / gridDim.x;

    const long rowBase = (long)by * 256;
    const long colBase = (long)bx * 256;

    const int c0 = tid, c1 = tid + 512;
    const int r0 = c0 >> 2, ch0 = (c0 & 3) ^ ((r0 >> 1) & 3);
    const int r1 = c1 >> 2, ch1 = (c1 & 3) ^ ((r1 >> 1) & 3);

    const u16* pa0 = A + (rowBase + r0) * (long)lda + ch0 * 8;
    const u16* pa1 = A + (rowBase + r1) * (long)lda + ch1 * 8;
    const u16* pb0 = B + (colBase + r0) * (long)ldb + ch0 * 8;
    const u16* pb1 = B + (colBase + r1) * (long)ldb + ch1 * 8;

    int aoff[8], boff[4];
    #pragma unroll
    for (int mi = 0; mi < 8; ++mi) {
        int r = wm * 128 + mi * 16 + lr;
        aoff[mi] = r * 32 + ((kg ^ ((r >> 1) & 3)) << 3);
    }
    #pragma unroll
    for (int ni = 0; ni < 4; ++ni) {
        int c = wn * 64 + ni * 16 + lr;
        boff[ni] = c * 32 + ((kg ^ ((c >> 1) & 3)) << 3);
    }

    floatx4 acc[8][4];
    #pragma unroll
    for (int mi = 0; mi < 8; ++mi)
        #pragma unroll
        for (int ni = 0; ni < 4; ++ni)
            acc[mi][ni] = (floatx4)0.f;

    auto stageA = [&](int buf, int kt) {
        gload16(pa0 + (long)kt * 32, &As[buf][c0 * 8]);
        gload16(pa1 + (long)kt * 32, &As[buf][c1 * 8]);
    };
    auto stageB = [&](int buf, int kt) {
        gload16(pb0 + (long)kt * 32, &Bs[buf][c0 * 8]);
        gload16(pb1 + (long)kt * 32, &Bs[buf][c1 * 8]);
    };

    const int NT = K / 32;
    stageA(0, 0); stageB(0, 0);
    stageA(1, 1); stageB(1, 1);
    asm volatile("s_waitcnt vmcnt(4)" ::: "memory");
    __builtin_amdgcn_sched_barrier(0);
    __builtin_amdgcn_s_barrier();

    int b0 = 0, b1 = 1, b2 = 2;
    for (int t = 0; t < NT; ++t) {
        bf16x8 afr[4], bfr[4];
        if (t + 2 < NT) stageA(b2, t + 2);
        #pragma unroll
        for (int mi = 0; mi < 4; ++mi) afr[mi] = *(const bf16x8*)(&As[b0][aoff[mi]]);
        #pragma unroll
        for (int ni = 0; ni < 4; ++ni) bfr[ni] = *(const bf16x8*)(&Bs[b0][boff[ni]]);
        __builtin_amdgcn_s_barrier();
        asm volatile("s_waitcnt lgkmcnt(0)" ::: "memory");
        __builtin_amdgcn_sched_barrier(0);
        __builtin_amdgcn_s_setprio(1);
        #pragma unroll
        for (int mi = 0; mi < 4; ++mi)
            #pragma unroll
            for (int ni = 0; ni < 4; ++ni)
                acc[mi][ni] = __builtin_amdgcn_mfma_f32_16x16x32_bf16(
                                  afr[mi], bfr[ni], acc[mi][ni], 0, 0, 0);
        __builtin_amdgcn_s_setprio(0);
        __builtin_amdgcn_sched_barrier(0);
        __builtin_amdgcn_s_barrier();
        if (t + 2 < NT) stageB(b2, t + 2);
        #pragma unroll
        for (int mi = 0; mi < 4; ++mi) afr[mi] = *(const bf16x8*)(&As[b0][aoff[4 + mi]]);
        __builtin_amdgcn_s_barrier();
        asm volatile("s_waitcnt lgkmcnt(0)" ::: "memory");
        __builtin_amdgcn_sched_barrier(0);
        __builtin_amdgcn_s_setprio(1);
        #pragma unroll
        for (int mi = 0; mi < 4; ++mi)
            #pragma unroll
            for (int ni = 0; ni < 4; ++ni)
                acc[4 + mi][ni] = __builtin_amdgcn_mfma_f32_16x16x32_bf16(
                                      afr[mi], bfr[ni], acc[4 + mi][ni], 0, 0, 0);
        __builtin_amdgcn_s_setprio(0);
        __builtin_amdgcn_sched_barrier(0);
        if (t + 2 < NT) { asm volatile("s_waitcnt vmcnt(4)" ::: "memory"); }
        else            { asm volatile("s_waitcnt vmcnt(0)" ::: "memory"); }
        __builtin_amdgcn_sched_barrier(0);
        __builtin_amdgcn_s_barrier();
        int tb = b0; b0 = b1; b1 = b2; b2 = tb;
    }

    const long col0 = colBase + wn * 64 + lr;
    const long row0 = rowBase + wm * 128 + kg * 4;
    #pragma unroll
    for (int ni = 0; ni < 4; ++ni) {
        long col = col0 + ni * 16;
        float bv = BIAS ? bias[col] : 0.f;
        #pragma unroll
        for (int mi = 0; mi < 8; ++mi)
            #pragma unroll
            for (int j = 0; j < 4; ++j) {
                float v = acc[mi][ni][j] * alpha + bv;
                if (RELU) v = fmaxf(v, 0.f);
                if (OBF) ((u16*)Cv)[(row0 + mi * 16 + j) * (long)ldc + col] = f2bf(v);
                else     ((float*)Cv)[(row0 + mi * 16 + j) * (long)ldc + col] = v;
            }
    }
}

// ---------------------------------------------------------------------------
// fp32 [R][C] -> bf16 [C][R] weight transpose-convert. 64x64 tiles.
__global__ __launch_bounds__(256) void tcvt(
    const float* __restrict__ in, u16* __restrict__ out,
    int ldIn, int ldOut, long sIn, long sOut)
{
    __shared__ u16 t[64][68];
    const int tx = threadIdx.x & 15;
    const int ty = threadIdx.x >> 4;
    const long r0 = (long)blockIdx.y * 64, c0 = (long)blockIdx.x * 64;
    const float* ib = in + (long)blockIdx.z * sIn;
    u16* ob = out + (long)blockIdx.z * sOut;
    #pragma unroll
    for (int j = 0; j < 4; ++j) {
        int r = ty + j * 16;
        float4 v = *(const float4*)&ib[(r0 + r) * (long)ldIn + c0 + tx * 4];
        u16x4 q = { f2bf(v.x), f2bf(v.y), f2bf(v.z), f2bf(v.w) };
        *(u16x4*)&t[r][tx * 4] = q;
    }
    __syncthreads();
    #pragma unroll
    for (int j = 0; j < 4; ++j) {
        int c = ty + j * 16;
        u16x4 q = { t[tx*4+0][c], t[tx*4+1][c], t[tx*4+2][c], t[tx*4+3][c] };
        *(u16x4*)&ob[(c0 + c) * (long)ldOut + r0 + tx * 4] = q;
    }
}

// ---------------------------------------------------------------------------
__global__ __launch_bounds__(256) void gather_kernel(
    const int* __restrict__ seq, const float* __restrict__ embed,
    u16* __restrict__ xb)
{
    int t = blockIdx.x;
    int tok = seq[t];
    const float* src = embed + (long)tok * E_;
    long base = (long)t * E_;
    #pragma unroll
    for (int j = 0; j < 3; ++j) {
        int i = threadIdx.x + j * 256;
        xb[base + i] = f2bf(src[i]);
    }
}

// ---------------------------------------------------------------------------
__global__ __launch_bounds__(384) void rope_tab_kernel(float2* __restrict__ tab)
{
    int s = blockIdx.x;
    int i = threadIdx.x;
    float inv = expf(-(float)(2 * i) * (9.210340371976184f / (float)E_));
    float ang = (float)s * inv;
    float sn, cs;
    sincosf(ang, &sn, &cs);
    tab[(long)s * 384 + i] = make_float2(cs, sn);
}

// ---------------------------------------------------------------------------
// In-place softmax on bf16 scores (scale pre-applied). One WAVE per row,
// 4 rows per block; 16 elems/lane via 16B loads; pure shuffle reduce.
__global__ __launch_bounds__(256) void softmax_kernel(
    u16* __restrict__ P, int causal)
{
    const int w = threadIdx.x >> 6;
    const int lane = threadIdx.x & 63;
    const long row = (long)blockIdx.x * 4 + w;
    const int s = (int)(row & (S_ - 1));
    u16* p = P + row * S_;
    const int c0 = lane * 16;

    u16x8 a = *(const u16x8*)(p + c0);
    u16x8 b = *(const u16x8*)(p + c0 + 8);
    float v[16];
    float mx = -INFINITY;
    #pragma unroll
    for (int j = 0; j < 8; ++j) {
        float x = bf2f((u16)a[j]);
        if (causal && c0 + j > s) x = -INFINITY;
        v[j] = x; mx = fmaxf(mx, x);
    }
    #pragma unroll
    for (int j = 0; j < 8; ++j) {
        float x = bf2f((u16)b[j]);
        if (causal && c0 + 8 + j > s) x = -INFINITY;
        v[8 + j] = x; mx = fmaxf(mx, x);
    }
    #pragma unroll
    for (int off = 1; off < 64; off <<= 1)
        mx = fmaxf(mx, __shfl_xor(mx, off, 64));

    float sum = 0.f;
    #pragma unroll
    for (int j = 0; j < 16; ++j) {
        v[j] = __expf(v[j] - mx);
        sum += v[j];
    }
    #pragma unroll
    for (int off = 1; off < 64; off <<= 1)
        sum += __shfl_xor(sum, off, 64);

    float invs = 1.f / sum;
    u16x8 oa, ob;
    #pragma unroll
    for (int j = 0; j < 8; ++j) oa[j] = f2bf(v[j] * invs);
    #pragma unroll
    for (int j = 0; j < 8; ++j) ob[j] = f2bf(v[8 + j] * invs);
    *(u16x8*)(p + c0) = oa;
    *(u16x8*)(p + c0 + 8) = ob;
}

// ---------------------------------------------------------------------------
// xout = LN(xin + hin)*g + b, all bf16 (fp32 stats). One WAVE per row.
__global__ __launch_bounds__(256) void add_ln_kernel(
    const u16* __restrict__ xin, const u16* __restrict__ hin,
    const float* __restrict__ gb, u16* __restrict__ xout)
{
    int row = blockIdx.x * 4 + (threadIdx.x >> 6);
    int lane = threadIdx.x & 63;
    const u16x4* xr = (const u16x4*)(xin + (long)row * E_);
    const u16x4* hr = (const u16x4*)(hin + (long)row * E_);

    float4 v[3];
    float sum = 0.f, sq = 0.f;
    #pragma unroll
    for (int l = 0; l < 3; ++l) {
        int idx = l * 64 + lane;
        u16x4 a = xr[idx];
        u16x4 b = hr[idx];
        v[l].x = bf2f(a[0]) + bf2f(b[0]);
        v[l].y = bf2f(a[1]) + bf2f(b[1]);
        v[l].z = bf2f(a[2]) + bf2f(b[2]);
        v[l].w = bf2f(a[3]) + bf2f(b[3]);
        sum += v[l].x + v[l].y + v[l].z + v[l].w;
        sq  += v[l].x*v[l].x + v[l].y*v[l].y + v[l].z*v[l].z + v[l].w*v[l].w;
    }
    #pragma unroll
    for (int off = 1; off < 64; off <<= 1) {
        sum += __shfl_xor(sum, off, 64);
        sq  += __shfl_xor(sq,  off, 64);
    }

    float mu  = sum * (1.f / E_);
    float var = sq * (1.f / E_) - mu * mu;
    float inv = rsqrtf(var + 1e-5f);

    const float4* g4 = (const float4*)gb;
    const float4* b4 = (const float4*)(gb + E_);
    u16x4* xo = (u16x4*)(xout + (long)row * E_);
    #pragma unroll
    for (int l = 0; l < 3; ++l) {
        int idx = l * 64 + lane;
        float4 g = g4[idx], bb = b4[idx];
        u16x4 ob;
        ob[0] = f2bf((v[l].x - mu) * inv * g.x + bb.x);
        ob[1] = f2bf((v[l].y - mu) * inv * g.y + bb.y);
        ob[2] = f2bf((v[l].z - mu) * inv * g.z + bb.z);
        ob[3] = f2bf((v[l].w - mu) * inv * g.w + bb.w);
        xo[idx] = ob;
    }
}

// ---------------------------------------------------------------------------
// MLP tail: h = relu(p0 + p1 + b2); xout = LN(xin + h)*g + b. One WAVE per row.
__global__ __launch_bounds__(256) void add_ln_mlp_kernel(
    const u16* __restrict__ xin, const u16* __restrict__ part,
    const float* __restrict__ b2, const float* __restrict__ gb,
    u16* __restrict__ xout)
{
    const long TE = (long)T_TOK * E_;
    int row = blockIdx.x * 4 + (threadIdx.x >> 6);
    int lane = threadIdx.x & 63;
    const u16x4* xr = (const u16x4*)(xin + (long)row * E_);
    const u16x4* p0 = (const u16x4*)(part + (long)row * E_);
    const u16x4* p1 = (const u16x4*)(part + TE + (long)row * E_);
    const float4* b24 = (const float4*)b2;

    float4 v[3];
    float sum = 0.f, sq = 0.f;
    #pragma unroll
    for (int l = 0; l < 3; ++l) {
        int idx = l * 64 + lane;
        u16x4 a = xr[idx];
        u16x4 h0 = p0[idx];
        u16x4 h1 = p1[idx];
        float4 bv = b24[idx];
        float h;
        h = fmaxf(bf2f(h0[0]) + bf2f(h1[0]) + bv.x, 0.f); v[l].x = bf2f(a[0]) + h;
        h = fmaxf(bf2f(h0[1]) + bf2f(h1[1]) + bv.y, 0.f); v[l].y = bf2f(a[1]) + h;
        h = fmaxf(bf2f(h0[2]) + bf2f(h1[2]) + bv.z, 0.f); v[l].z = bf2f(a[2]) + h;
        h = fmaxf(bf2f(h0[3]) + bf2f(h1[3]) + bv.w, 0.f); v[l].w = bf2f(a[3]) + h;
        sum += v[l].x + v[l].y + v[l].z + v[l].w;
        sq  += v[l].x*v[l].x + v[l].y*v[l].y + v[l].z*v[l].z + v[l].w*v[l].w;
    }
    #pragma unroll
    for (int off = 1; off < 64; off <<= 1) {
        sum += __shfl_xor(sum, off, 64);
        sq  += __shfl_xor(sq,  off, 64);
    }

    float mu  = sum * (1.f / E_);
    float var = sq * (1.f / E_) - mu * mu;
    float inv = rsqrtf(var + 1e-5f);

    const float4* g4 = (const float4*)gb;
    const float4* b4 = (const float4*)(gb + E_);
    u16x4* xo = (u16x4*)(xout + (long)row * E_);
    #pragma unroll
    for (int l = 0; l < 3; ++l) {
        int idx = l * 64 + lane;
        float4 g = g4[idx], bb = b4[idx];
        u16x4 ob;
        ob[0] = f2bf((v[l].x - mu) * inv * g.x + bb.x);
        ob[1] = f2bf((v[l].y - mu) * inv * g.y + bb.y);
        ob[2] = f2bf((v[l].z - mu) * inv * g.z + bb.z);
        ob[3] = f2bf((v[l].w - mu) * inv * g.w + bb.w);
        xo[idx] = ob;
    }
}

// ---------------------------------------------------------------------------
extern "C" void kernel_launch(void* const* d_in, const int* in_sizes, int n_in,
                              void* d_out, int out_size, void* d_ws, size_t ws_size,
                              hipStream_t stream) {
    const int*   seq       = (const int*)d_in[0];
    const float* embed     = (const float*)d_in[2];
    const float* enc_qkv_w = (const float*)d_in[3];
    const float* enc_qkv_b = (const float*)d_in[4];
    const float* enc_ln    = (const float*)d_in[5];
    const float* enc_w1    = (const float*)d_in[6];
    const float* enc_b1    = (const float*)d_in[7];
    const float* enc_w2    = (const float*)d_in[8];
    const float* enc_b2    = (const float*)d_in[9];
    const float* dec_qkv_w = (const float*)d_in[10];
    const float* dec_qkv_b = (const float*)d_in[11];
    const float* dec_ln    = (const float*)d_in[12];
    const float* dec_w1    = (const float*)d_in[13];
    const float* dec_b1    = (const float*)d_in[14];
    const float* dec_w2    = (const float*)d_in[15];
    const float* dec_b2    = (const float*)d_in[16];
    const float* unembed   = (const float*)d_in[17];

    const long TE  = (long)T_TOK * E_;
    const long SE  = (long)S_ * E_;
    const long SS  = (long)S_ * S_;
    const long EE  = (long)E_ * E_;
    const long EH  = (long)E_ * H_;
    const long VE  = (long)V_ * E_;
    const long SQK = (long)S_ * 1536;
    const long TABF = (long)S_ * 384 * 2;   // floats

    float*  ws    = (float*)d_ws;
    float2* f_tab = (float2*)ws;

    u16* u_emb = (u16*)(ws + TABF);     // TE
    u16* u_x   = u_emb + TE;            // TE  (bf16 residual state)
    u16* u_h   = u_x + TE;              // TE  (attn output)
    u16* u_enc = u_h + TE;              // 5*TE
    u16* u_R   = u_enc + 5 * TE;        // 4*TE: qk(2TE)+vT(TE) | hid(4TE)
    u16* u_s2  = u_R + 4 * TE;          // 2*TE: P | mlp partials
    u16* u_ck  = u_s2 + 2 * TE;         // 5*TE  cross-K [T][768] per layer
    u16* u_cv  = u_ck + 5 * TE;         // 5*TE  cross-V^T [768][T] per layer
    u16* u_w   = u_cv + 5 * TE;         // weights

    u16* u_qk  = u_R;
    u16* u_vT  = u_R + 2 * TE;
    u16* u_hid = u_R;
    u16* u_P   = u_s2;

    // weight region: MLP+unembed first (tier 1), QKV after (tier 2)
    u16* pw_ew1  = u_w;
    u16* pw_ew2  = pw_ew1 + 5 * EH;
    u16* pw_dw1  = pw_ew2 + 5 * EH;
    u16* pw_dw2  = pw_dw1 + 5 * EH;
    u16* pw_un   = pw_dw2 + 5 * EH;
    u16* pw_eqkv = pw_un + VE;
    u16* pw_dqkv = pw_eqkv + 15 * EE;

    size_t need_full = (size_t)((char*)(pw_dqkv + 30 * EE) - (char*)d_ws);
    size_t need_mid  = (size_t)((char*)(pw_eqkv + 2 * EE) - (char*)d_ws);
    bool pQKV = ws_size >= need_full;
    bool pMLP = ws_size >= need_mid;

    auto T = [&](const float* in, u16* out, int R, int C, int z) {
        dim3 g(C / 64, R / 64, z);
        tcvt<<<g, 256, 0, stream>>>(in, out, C, R, (long)R * C, (long)R * C);
    };
    auto WTq = [&](const float* w, int z, u16* pp) -> const u16* {
        if (pQKV) return pp;
        u16* dst = pMLP ? pw_eqkv : u_w;
        T(w, dst, E_, E_, z);
        return dst;
    };
    auto WTm = [&](const float* w, int R, int C, u16* pp) -> const u16* {
        if (pMLP) return pp;
        T(w, u_w, R, C, 1);
        return u_w;
    };

    if (pQKV) {
        T(enc_qkv_w, pw_eqkv, E_, E_, 15);
        T(dec_qkv_w, pw_dqkv, E_, E_, 30);
    }
    if (pMLP) {
        T(enc_w1, pw_ew1, E_, H_, L_);
        T(enc_w2, pw_ew2, H_, E_, L_);
        T(dec_w1, pw_dw1, E_, H_, L_);
        T(dec_w2, pw_dw2, H_, E_, L_);
        T(unembed, pw_un, E_, V_, 1);
    }

    rope_tab_kernel<<<S_, 384, 0, stream>>>(f_tab);
    gather_kernel<<<T_TOK, 256, 0, stream>>>(seq, embed, u_emb);

    const float SCALE = 0.03608439182435161f; // 1/sqrt(768)

    // --- per-op launchers -------------------------------------------------
    auto qk_rope = [&](const u16* X, const u16* W, const float* bias) {
        dim3 g(1536 / 128, T_TOK / 128, 1);   // 128^2 tile (reverted)
        mgemm<1,0,1,1><<<g,256,0,stream>>>(X, W, u_qk, bias, f_tab, 1.f,
            T_TOK, 1536, E_, E_, E_, 1536, 0, 0, 0, 0);
    };
    auto proj_rope64 = [&](const u16* X, const u16* W, u16* dst, const float* bias,
                           int ldc) {
        dim3 g(768 / 128, T_TOK / 64, 1);
        mgemm64<1,0,1,1><<<g,256,0,stream>>>(X, W, dst, bias, f_tab, 1.f,
            T_TOK, 768, E_, E_, E_, ldc, 0, 0, 0, 0, 0);
    };
    auto vT_gemm = [&](const u16* Wv, const u16* X, u16* dst, const float* biasrow) {
        dim3 g(T_TOK / 128, 768 / 64, 1);
        mgemm64<1,0,2,0><<<g,256,0,stream>>>(Wv, X, dst, biasrow, nullptr, 1.f,
            768, T_TOK, E_, E_, E_, T_TOK, 0, 0, 0, 0, 0);
    };
    auto qkt = [&](const u16* Kp, int ldbK, long sB, int causal) {
        dim3 g(S_ / 128, S_ / 64, B_);
        mgemm64<1,0,0,0><<<g,256,0,stream>>>(u_qk, Kp, u_P, nullptr, nullptr,
            SCALE, S_, S_, E_, 1536, ldbK, S_, SQK, sB, SS, 0, causal ? 1 : 0);
    };
    auto pv = [&](const u16* Vp, int causal) {
        dim3 g(E_ / 128, S_ / 64, B_);
        mgemm64<1,0,0,0><<<g,256,0,stream>>>(u_P, Vp, u_h, nullptr, nullptr, 1.f,
            S_, E_, S_, S_, T_TOK, E_, SS, 1024, SE, 0, causal ? 2 : 0);
    };
    auto mlp1 = [&](const u16* X, const u16* W, const float* b1) {
        dim3 g(H_ / 128, T_TOK / 128, 1);
        mgemm<1,1,1,0><<<g,256,0,stream>>>(X, W, u_hid, b1, nullptr, 1.f,
            T_TOK, H_, E_, E_, E_, H_, 0, 0, 0, 0);
    };
    auto mlp2 = [&](const u16* W) {
        dim3 g(E_ / 128, T_TOK / 128, 2);
        mgemm<1,0,0,0><<<g,256,0,stream>>>(u_hid, W, u_s2 + 0, nullptr, nullptr, 1.f,
            T_TOK, E_, 1536, H_, H_, E_, 1536, 1536, TE, 0);
    };
    auto lnz = [&](const u16* xin, const float* gb, u16* xbdst) {
        add_ln_kernel<<<T_TOK / 4, 256, 0, stream>>>(xin, u_h, gb, xbdst);
    };
    auto lnmlp = [&](const u16* xin, const float* b2, const float* gb, u16* xbdst) {
        add_ln_mlp_kernel<<<T_TOK / 4, 256, 0, stream>>>(xin, u_s2, b2, gb, xbdst);
    };
    auto sm = [&](int causal) {
        softmax_kernel<<<T_TOK / 4, 256, 0, stream>>>(u_P, causal);
    };

    // ------------------------ encoder ------------------------
    for (int i = 0; i < L_; ++i) {
        const u16* xsrc = (i == 0) ? u_emb : u_enc + (long)(i - 1) * TE;
        const float* bb = enc_qkv_b + (long)i * 3 * E_;
        qk_rope(xsrc, WTq(enc_qkv_w + (long)i * 3 * EE, 2,
                          pw_eqkv + (long)i * 3 * EE), bb);
        vT_gemm(WTq(enc_qkv_w + ((long)i * 3 + 2) * EE, 1,
                    pw_eqkv + ((long)i * 3 + 2) * EE), xsrc, u_vT, bb + 2 * E_);
        qkt(u_qk + 768, 1536, SQK, 0);
        sm(0);
        pv(u_vT, 0);
        lnz(xsrc, enc_ln + (2L * i + 0) * 2 * E_, u_x);
        mlp1(u_x, WTm(enc_w1 + (long)i * EH, E_, H_, pw_ew1 + (long)i * EH),
             enc_b1 + (long)i * H_);
        mlp2(WTm(enc_w2 + (long)i * EH, H_, E_, pw_ew2 + (long)i * EH));
        lnmlp(u_x, enc_b2 + (long)i * E_, enc_ln + (2L * i + 1) * 2 * E_,
              u_enc + (long)i * TE);
    }

    // ---- batched cross-attention K/V precompute (z = 5 layers) ----
    if (pQKV) {
        {   // cross K: [T][768] per layer, roped, per-col bias (stride 6E)
            dim3 g(768 / 128, T_TOK / 64, L_);
            mgemm64<1,0,1,1><<<g,256,0,stream>>>(
                u_enc, pw_dqkv + 4 * EE, u_ck, dec_qkv_b + 4 * E_, f_tab, 1.f,
                T_TOK, 768, E_, E_, E_, 768, TE, 6 * EE, TE, 6 * E_, 0);
        }
        {   // cross V^T: [768][T] per layer, per-row bias (stride 6E)
            dim3 g(T_TOK / 128, 768 / 64, L_);
            mgemm64<1,0,2,0><<<g,256,0,stream>>>(
                pw_dqkv + 5 * EE, u_enc, u_cv, dec_qkv_b + 5 * E_, nullptr, 1.f,
                768, T_TOK, E_, E_, E_, T_TOK, 6 * EE, TE, TE, 6 * E_, 0);
        }
    }

    // ------------------------ decoder ------------------------
    for (int i = 0; i < L_; ++i) {
        const u16* xs = (i == 0) ? u_emb : u_x;   // no seed copy
        const u16* kv_bf = u_enc + (long)i * TE;
        const float* bb = dec_qkv_b + (long)i * 6 * E_;

        // self-attention (causal)
        qk_rope(xs, WTq(dec_qkv_w + (long)i * 6 * EE, 2,
                        pw_dqkv + (long)i * 6 * EE), bb);
        vT_gemm(WTq(dec_qkv_w + ((long)i * 6 + 2) * EE, 1,
                    pw_dqkv + ((long)i * 6 + 2) * EE), xs, u_vT, bb + 2 * E_);
        qkt(u_qk + 768, 1536, SQK, 1);
        sm(1);
        pv(u_vT, 1);
        lnz(xs, dec_ln + (3L * i + 0) * 2 * E_, u_x);

        // cross-attention: Q per layer; K/V precomputed (batched) if pQKV
        proj_rope64(u_x, WTq(dec_qkv_w + ((long)i * 6 + 3) * EE, 1,
                             pw_dqkv + ((long)i * 6 + 3) * EE), u_qk, bb + 3 * E_, 1536);
        const u16* Vc;
        if (pQKV) {
            qkt(u_ck + (long)i * TE, 768, SE, 0);
            Vc = u_cv + (long)i * TE;
        } else {
            proj_rope64(kv_bf, WTq(dec_qkv_w + ((long)i * 6 + 4) * EE, 1, nullptr),
                        u_qk + 768, bb + 4 * E_, 1536);
            vT_gemm(WTq(dec_qkv_w + ((long)i * 6 + 5) * EE, 1, nullptr),
                    kv_bf, u_vT, bb + 5 * E_);
            qkt(u_qk + 768, 1536, SQK, 0);
            Vc = u_vT;
        }
        sm(0);
        pv(Vc, 0);
        lnz(u_x, dec_ln + (3L * i + 1) * 2 * E_, u_x);

        // MLP
        mlp1(u_x, WTm(dec_w1 + (long)i * EH, E_, H_, pw_dw1 + (long)i * EH),
             dec_b1 + (long)i * H_);
        mlp2(WTm(dec_w2 + (long)i * EH, H_, E_, pw_dw2 + (long)i * EH));
        lnmlp(u_x, dec_b2 + (long)i * E_, dec_ln + (3L * i + 2) * 2 * E_, u_x);
    }

    // ------------------------ unembed ------------------------
    {
        dim3 g(V_ / 256, T_TOK / 256, 1);
        mgemm8<0,0,0><<<g,512,0,stream>>>(u_x, WTm(unembed, E_, V_, pw_un),
            d_out, nullptr, 1.f, T_TOK, V_, E_, E_, E_, V_);
    }
}